// Round 1
// baseline (29.105 us; speedup 1.0000x reference)
//
#include <hip/hip_runtime.h>

// out[b,i] = sum_j A[z_b][i][j] * x[b,j]  -  dt * x[b,i]^3
// A[m] = dt*beta_m*W_m + diag(1 + dt*(mu_m + alpha_m*deg_m))
// W_m = sigmoid(0.5*(G_m + G_m^T)) with zero diagonal; deg_m = row-sum of W_m.

__global__ __launch_bounds__(256) void bistable_kernel(
    const float* __restrict__ X,          // (B,4)
    const int*   __restrict__ z,          // (B,)
    const float* __restrict__ dt_val,     // (1,)
    const float* __restrict__ G,          // (4,4,4)
    const float* __restrict__ mu_logits,  // (4,4)
    const float* __restrict__ alpha_p,    // (4,)
    const float* __restrict__ beta_p,     // (4,)
    float* __restrict__ out,              // (B,4)
    int Bn)
{
    __shared__ float A[4 * 16];
    __shared__ float s_dt;

    const int t = threadIdx.x;
    if (t < 16) {
        const int m = t >> 2;      // mode
        const int i = t & 3;       // row
        const float dt = dt_val[0];
        float w[4];
        float deg = 0.0f;
        #pragma unroll
        for (int j = 0; j < 4; ++j) {
            float s = 0.5f * (G[m * 16 + i * 4 + j] + G[m * 16 + j * 4 + i]);
            float wv = 1.0f / (1.0f + __expf(-s));
            if (j == i) wv = 0.0f;   // zero diagonal
            w[j] = wv;
            deg += wv;
        }
        const float mu = 0.1f + 1.4f / (1.0f + __expf(-mu_logits[m * 4 + i]));
        const float a = alpha_p[m];
        const float b = beta_p[m];
        float arow[4];
        #pragma unroll
        for (int j = 0; j < 4; ++j) arow[j] = dt * b * w[j];
        arow[i] = 1.0f + dt * (mu + a * deg);   // fold diag (W diag is 0)
        #pragma unroll
        for (int j = 0; j < 4; ++j) A[m * 16 + i * 4 + j] = arow[j];
    }
    if (t == 0) s_dt = dt_val[0];
    __syncthreads();

    const float dt = s_dt;
    const float4* __restrict__ X4 = (const float4*)X;
    float4* __restrict__ O4 = (float4*)out;

    const int tid = blockIdx.x * blockDim.x + t;
    const int stride = gridDim.x * blockDim.x;
    for (int idx = tid; idx < Bn; idx += stride) {
        const float4 xv = X4[idx];
        const int m = z[idx];
        const float* __restrict__ a = &A[m * 16];
        const float x0 = xv.x, x1 = xv.y, x2 = xv.z, x3 = xv.w;

        float o0 = a[0]  * x0 + a[1]  * x1 + a[2]  * x2 + a[3]  * x3;
        float o1 = a[4]  * x0 + a[5]  * x1 + a[6]  * x2 + a[7]  * x3;
        float o2 = a[8]  * x0 + a[9]  * x1 + a[10] * x2 + a[11] * x3;
        float o3 = a[12] * x0 + a[13] * x1 + a[14] * x2 + a[15] * x3;

        o0 -= dt * x0 * x0 * x0;
        o1 -= dt * x1 * x1 * x1;
        o2 -= dt * x2 * x2 * x2;
        o3 -= dt * x3 * x3 * x3;

        O4[idx] = make_float4(o0, o1, o2, o3);
    }
}

extern "C" void kernel_launch(void* const* d_in, const int* in_sizes, int n_in,
                              void* d_out, int out_size, void* d_ws, size_t ws_size,
                              hipStream_t stream) {
    const float* X         = (const float*)d_in[0];
    const int*   z         = (const int*)d_in[1];
    const float* dt_val    = (const float*)d_in[2];
    const float* G         = (const float*)d_in[3];
    const float* mu_logits = (const float*)d_in[4];
    const float* alpha_p   = (const float*)d_in[5];
    const float* beta_p    = (const float*)d_in[6];
    float* out = (float*)d_out;

    const int Bn = in_sizes[1];   // number of items (z count)

    const int block = 256;
    int grid = (Bn + block - 1) / block;
    if (grid > 2048) grid = 2048;

    bistable_kernel<<<grid, block, 0, stream>>>(X, z, dt_val, G, mu_logits,
                                                alpha_p, beta_p, out, Bn);
}